// Round 10
// baseline (135.812 us; speedup 1.0000x reference)
//
#include <hip/hip_runtime.h>
#include <cstddef>
#include <cstdint>

// Problem constants: S=8, N=50000, F=5, DEG=32, D_IN=D_OUT=128
static constexpr int S_    = 8;
static constexpr int N_    = 50000;
static constexpr int F_    = 5;
static constexpr int DEG_  = 32;
static constexpr int DOUT_ = 128;
static constexpr int TOTAL_NODES = S_ * N_;      // 400000

// LDS-staged gather geometry
static constexpr int BLK   = 640;                // threads/block = 10 waves
static constexpr int BPS   = 79;                 // blocks/sample (79*640=50560)
static constexpr int SLICE = 12500;              // table rows per pass
static constexpr int NPASS = 4;                  // 4*12500 = 50000 exact
static constexpr int SLICE_DW  = SLICE * 3;      // 37500 dwords/slice
static constexpr int SLICE_I4  = SLICE_DW / 4;   // 9375 int4/slice

typedef float    f32x4 __attribute__((ext_vector_type(4)));
typedef int      i32x4 __attribute__((ext_vector_type(4)));
typedef _Float16 h2    __attribute__((ext_vector_type(2)));

// ---------------------------------------------------------------------------
// Kernel 1: fuse W_1 [5][128] with W [256][128] into Wc [2][5][128].
// ---------------------------------------------------------------------------
__global__ void wc_precompute(const float* __restrict__ W1,
                              const float* __restrict__ W,
                              float* __restrict__ Wc) {
    int t = blockIdx.x * blockDim.x + threadIdx.x;
    if (t >= 2 * F_ * DOUT_) return;
    int o = t & (DOUT_ - 1);
    int f = (t >> 7) % F_;
    int p = t / (F_ * DOUT_);
    const float* w1r  = W1 + f * 128;
    const float* wcol = W + (size_t)p * 128 * DOUT_ + o;
    float acc = 0.f;
#pragma unroll 8
    for (int d = 0; d < 128; ++d)
        acc = fmaf(w1r[d], wcol[(size_t)d * DOUT_], acc);
    Wc[t] = acc;
}

// ---------------------------------------------------------------------------
// Kernel 2: pack x rows into 12B f16 rows (6 halves: f0..f4 + zero pad).
// Table = 400000 * 12B = 4.8 MB; read back COALESCED during staging.
// ---------------------------------------------------------------------------
__global__ __launch_bounds__(256) void xpack_h6(const float* __restrict__ x,
                                                int* __restrict__ xh6) {
    int t = blockIdx.x * blockDim.x + threadIdx.x;
    if (t >= TOTAL_NODES) return;
    const float* r = x + (size_t)t * F_;
    h2 p0 = { (_Float16)r[0], (_Float16)r[1] };
    h2 p1 = { (_Float16)r[2], (_Float16)r[3] };
    h2 p2 = { (_Float16)r[4], (_Float16)0.f };
    xh6[3 * t + 0] = __builtin_bit_cast(int, p0);
    xh6[3 * t + 1] = __builtin_bit_cast(int, p1);
    xh6[3 * t + 2] = __builtin_bit_cast(int, p2);
}

// ---------------------------------------------------------------------------
// Kernel 3: encoder v10 — LDS-staged gather.
//   Grid = S * BPS blocks; block handles 640 consecutive nodes of ONE sample.
//   Each thread owns one node (its 32 ids live in 8 VGPR quads).
//   4 passes: stage 12500-row slice (146.5 KB) coalesced into LDS, then each
//   thread accumulates ALL 32 ids branchlessly — out-of-slice ids clamp to a
//   zeroed dummy row (index SLICE). Packed-f16 adds, no unpack per read.
//   Phase B: v8-style — sums -> LDS transpose, halves produce 2 nodes/iter,
//   exact fp32 self features, 1/DEG folded into neighbor weights, nt stores.
// ---------------------------------------------------------------------------
__global__ __launch_bounds__(BLK) void encoder_v10(
    const int*   __restrict__ idx,   // [S][N][32]
    const int*   __restrict__ xh6,   // [S*N][3] dwords (f16x6 rows)
    const float* __restrict__ x,     // [S][N][5] fp32 (self, exact)
    const float* __restrict__ Wc,    // [2][5][128]
    const float* __restrict__ b,     // [128]
    float* __restrict__ out) {       // [S][N][128]
    __shared__ int lds[SLICE_DW + 4];            // 150,016 B (dummy row @ SLICE)
    const int tid  = threadIdx.x;
    const int s    = blockIdx.x / BPS;
    const int nb0  = (blockIdx.x % BPS) * BLK;   // local node base
    const int nl_s = nb0 + tid;                  // this thread's local node
    const bool valid = nl_s < N_;
    const int  gnode = s * N_ + (valid ? nl_s : (N_ - 1));

    // All 32 neighbor ids -> registers (coalesced: 128B/thread contiguous).
    i32x4 ids[8];
    const i32x4* irow = reinterpret_cast<const i32x4*>(idx + (size_t)gnode * DEG_);
#pragma unroll
    for (int t = 0; t < 8; ++t) ids[t] = irow[t];

    if (tid == 0) {                              // zero dummy row once
        lds[SLICE_DW] = 0; lds[SLICE_DW + 1] = 0; lds[SLICE_DW + 2] = 0;
    }

    h2 a0 = { (_Float16)0.f, (_Float16)0.f };
    h2 a1 = a0, a2 = a0;
    const i32x4* src4 = reinterpret_cast<const i32x4*>(xh6) + (size_t)s * (SLICE_I4 * NPASS);
    i32x4* lds4 = reinterpret_cast<i32x4*>(lds);

    for (int p = 0; p < NPASS; ++p) {
        __syncthreads();                         // prior pass readers done
        const i32x4* ps = src4 + p * SLICE_I4;
        for (int i = tid; i < SLICE_I4; i += BLK)
            lds4[i] = ps[i];                     // coalesced stream, L2/L3-hot
        __syncthreads();
        const int lo = p * SLICE;
#pragma unroll
        for (int k = 0; k < DEG_; ++k) {
            const int id  = ids[k >> 2][k & 3];
            const unsigned d = (unsigned)(id - lo);
            const int r   = (d < (unsigned)SLICE) ? (int)d : SLICE;  // clamp->0-row
            const int ba  = r * 3;
            const int w0 = lds[ba], w1 = lds[ba + 1], w2 = lds[ba + 2];
            a0 += __builtin_bit_cast(h2, w0);
            a1 += __builtin_bit_cast(h2, w1);
            a2 += __builtin_bit_cast(h2, w2);
        }
    }

    // ---- transpose sums via LDS (pass data dead) ----
    __syncthreads();
    lds[tid * 3 + 0] = __builtin_bit_cast(int, a0);
    lds[tid * 3 + 1] = __builtin_bit_cast(int, a1);
    lds[tid * 3 + 2] = __builtin_bit_cast(int, a2);
    __syncthreads();

    // ---- Phase B: MLP + relu + nt store (v8-proven layout) ----
    const int lane = tid & 63;
    const int wv   = tid >> 6;                   // 0..9, wave covers 64 nodes
    const int sl   = lane & 31;
    const int half = lane >> 5;
    const int o0   = sl << 2;
    const float inv = 1.f / DEG_;

    float wa[F_][4], wb[F_][4];
#pragma unroll
    for (int f = 0; f < F_; ++f) {
        f32x4 a  = *reinterpret_cast<const f32x4*>(Wc + f * DOUT_ + o0);
        f32x4 bb = *reinterpret_cast<const f32x4*>(Wc + F_ * DOUT_ + f * DOUT_ + o0);
        wa[f][0] = a.x;        wa[f][1] = a.y;
        wa[f][2] = a.z;        wa[f][3] = a.w;
        wb[f][0] = bb.x * inv; wb[f][1] = bb.y * inv;   // fold mean(1/32)
        wb[f][2] = bb.z * inv; wb[f][3] = bb.w * inv;
    }
    const f32x4 bias = *reinterpret_cast<const f32x4*>(b + o0);

#pragma unroll 4
    for (int i = 0; i < 32; ++i) {
        const int nl = wv * 64 + 2 * i + half;   // local node for this half
        const int n  = nb0 + nl;
        if (n >= N_) continue;                   // only last block per sample
        const int node = s * N_ + n;
        const h2 b0 = __builtin_bit_cast(h2, lds[nl * 3 + 0]);
        const h2 b1 = __builtin_bit_cast(h2, lds[nl * 3 + 1]);
        const h2 b2 = __builtin_bit_cast(h2, lds[nl * 3 + 2]);
        const float nf[F_] = { (float)b0.x, (float)b0.y,
                               (float)b1.x, (float)b1.y, (float)b2.x };
        const float* xr = x + (size_t)node * F_;           // broadcast, exact
        const float sf[F_] = { xr[0], xr[1], xr[2], xr[3], xr[4] };
        float y0 = bias.x, y1 = bias.y, y2 = bias.z, y3 = bias.w;
#pragma unroll
        for (int f = 0; f < F_; ++f) {
            y0 = fmaf(sf[f], wa[f][0], y0); y0 = fmaf(nf[f], wb[f][0], y0);
            y1 = fmaf(sf[f], wa[f][1], y1); y1 = fmaf(nf[f], wb[f][1], y1);
            y2 = fmaf(sf[f], wa[f][2], y2); y2 = fmaf(nf[f], wb[f][2], y2);
            y3 = fmaf(sf[f], wa[f][3], y3); y3 = fmaf(nf[f], wb[f][3], y3);
        }
        f32x4 yv = { fmaxf(y0, 0.f), fmaxf(y1, 0.f),
                     fmaxf(y2, 0.f), fmaxf(y3, 0.f) };
        __builtin_nontemporal_store(yv,
            reinterpret_cast<f32x4*>(out + (size_t)node * DOUT_ + o0));
    }
}

// ---------------------------------------------------------------------------
// Fallback (fp32 fused path) if ws_size is too small.
// ---------------------------------------------------------------------------
__global__ __launch_bounds__(256) void encoder_f32(
    const float* __restrict__ x, const int* __restrict__ idx,
    const float* __restrict__ Wc, const float* __restrict__ b,
    float* __restrict__ out, int total_pairs) {
    const int lane = threadIdx.x & 63;
    const int sl   = lane & 31;
    const int half = lane >> 5;
    const int o0   = sl << 2;
    const int gwave  = (blockIdx.x * blockDim.x + threadIdx.x) >> 6;
    const int nwaves = (gridDim.x * blockDim.x) >> 6;
    float wa[F_][4], wb[F_][4];
#pragma unroll
    for (int f = 0; f < F_; ++f) {
        f32x4 a  = *reinterpret_cast<const f32x4*>(Wc + f * DOUT_ + o0);
        f32x4 bb = *reinterpret_cast<const f32x4*>(Wc + F_ * DOUT_ + f * DOUT_ + o0);
        wa[f][0] = a.x;  wa[f][1] = a.y;  wa[f][2] = a.z;  wa[f][3] = a.w;
        wb[f][0] = bb.x; wb[f][1] = bb.y; wb[f][2] = bb.z; wb[f][3] = bb.w;
    }
    const f32x4 bias = *reinterpret_cast<const f32x4*>(b + o0);
    for (int p = gwave; p < total_pairs; p += nwaves) {
        const int node = p * 2 + half;
        const int s    = node / N_;
        const int nb = idx[(size_t)node * DEG_ + sl];
        const float* xr = x + ((size_t)s * N_ + nb) * F_;
        float n0 = xr[0], n1 = xr[1], n2 = xr[2], n3 = xr[3], n4 = xr[4];
#pragma unroll
        for (int m = 1; m < 32; m <<= 1) {
            n0 += __shfl_xor(n0, m); n1 += __shfl_xor(n1, m); n2 += __shfl_xor(n2, m);
            n3 += __shfl_xor(n3, m); n4 += __shfl_xor(n4, m);
        }
        const float inv = 1.f / DEG_;
        const float nf[F_] = {n0 * inv, n1 * inv, n2 * inv, n3 * inv, n4 * inv};
        const float* xsp = x + (size_t)node * F_;
        const float sf[F_] = {xsp[0], xsp[1], xsp[2], xsp[3], xsp[4]};
        float y0 = bias.x, y1 = bias.y, y2 = bias.z, y3 = bias.w;
#pragma unroll
        for (int f = 0; f < F_; ++f) {
            y0 = fmaf(sf[f], wa[f][0], y0); y0 = fmaf(nf[f], wb[f][0], y0);
            y1 = fmaf(sf[f], wa[f][1], y1); y1 = fmaf(nf[f], wb[f][1], y1);
            y2 = fmaf(sf[f], wa[f][2], y2); y2 = fmaf(nf[f], wb[f][2], y2);
            y3 = fmaf(sf[f], wa[f][3], y3); y3 = fmaf(nf[f], wb[f][3], y3);
        }
        f32x4 yv = { fmaxf(y0, 0.f), fmaxf(y1, 0.f), fmaxf(y2, 0.f), fmaxf(y3, 0.f) };
        *reinterpret_cast<f32x4*>(out + (size_t)node * DOUT_ + o0) = yv;
    }
}

extern "C" void kernel_launch(void* const* d_in, const int* in_sizes, int n_in,
                              void* d_out, int out_size, void* d_ws, size_t ws_size,
                              hipStream_t stream) {
    const float* x   = (const float*)d_in[0];
    const int*   idx = (const int*)  d_in[1];
    const float* W1  = (const float*)d_in[2];
    const float* W   = (const float*)d_in[3];
    const float* b   = (const float*)d_in[4];
    float* out = (float*)d_out;

    const size_t wc_bytes  = (size_t)2 * F_ * DOUT_ * sizeof(float);  // 5120
    const size_t xh6_bytes = (size_t)TOTAL_NODES * 12;                // 4.8 MB
    float* Wc = (float*)d_ws;

    hipLaunchKernelGGL(wc_precompute, dim3(5), dim3(256), 0, stream, W1, W, Wc);

    if (ws_size >= wc_bytes + xh6_bytes) {
        int* xh6 = (int*)((char*)d_ws + wc_bytes);   // 5120 % 16 == 0
        hipLaunchKernelGGL(xpack_h6, dim3((TOTAL_NODES + 255) / 256), dim3(256),
                           0, stream, x, xh6);
        hipLaunchKernelGGL(encoder_v10, dim3(S_ * BPS), dim3(BLK), 0, stream,
                           idx, xh6, x, Wc, b, out);
    } else {
        hipLaunchKernelGGL(encoder_f32, dim3(2048), dim3(256), 0, stream,
                           x, idx, Wc, b, out, TOTAL_NODES / 2);
    }
}